// Round 3
// baseline (379.343 us; speedup 1.0000x reference)
//
#include <hip/hip_runtime.h>

#define D 256

typedef float f32x4 __attribute__((ext_vector_type(4)));
typedef short short8 __attribute__((ext_vector_type(8)));
typedef __bf16 bf16x8 __attribute__((ext_vector_type(8)));

static __device__ __forceinline__ short f2bs(float f) {
    __bf16 b = (__bf16)f;
    return __builtin_bit_cast(short, b);
}

// ---------------- precompute kernels (run every call; deterministic) ----------------

__global__ void pre_bc(const float* __restrict__ b_agg, const float* __restrict__ We1,
                       const float* __restrict__ be1, float* __restrict__ bc)
{
    int j = threadIdx.x;
    float acc = be1[j];
    for (int k = 0; k < D; ++k)
        acc += 2.f * b_agg[k] * We1[k * D + j];
    bc[j] = acc;
}

// Ws[i][k] = W_agg[i*D+k] + W_agg[(i+D)*D+k]; Wc[i][j] = sum_k Ws[i][k]*We1[k][j]
// stored transposed: WcT[j*D+i]
__global__ void pre_wct(const float* __restrict__ W_agg, const float* __restrict__ We1,
                        short* __restrict__ WcT)
{
    __shared__ float wsrow[D];
    int i = blockIdx.x, j = threadIdx.x;
    wsrow[j] = W_agg[i * D + j] + W_agg[(i + D) * D + j];
    __syncthreads();
    float acc = 0.f;
    for (int k = 0; k < D; ++k)
        acc += wsrow[k] * We1[k * D + j];
    WcT[j * D + i] = f2bs(acc);
}

__global__ void pre_wn1t(const float* __restrict__ Wn1, short* __restrict__ Wn1T)
{
    int i = blockIdx.x, j = threadIdx.x;
    Wn1T[j * D + i] = f2bs(Wn1[i * D + j]);
}

__global__ void pre_w2t(const float* __restrict__ We2, const float* __restrict__ Wn2,
                        short* __restrict__ We2T, short* __restrict__ Wn2T)
{
    int k = threadIdx.x;
    for (int c = 0; c < 16; ++c) {
        float ve = (c < 5) ? We2[k * 5 + c] : 0.f;
        float vn = (c < 2) ? Wn2[k * 2 + c] : 0.f;
        We2T[c * D + k] = f2bs(ve);
        Wn2T[c * D + k] = f2bs(vn);
    }
}

// node_feat (fp32) -> bf16 cache in ws
__global__ void pre_featb(const float* __restrict__ f, short* __restrict__ o, int n8)
{
    int i = blockIdx.x * blockDim.x + threadIdx.x;
    if (i >= n8) return;
    const float4* p = reinterpret_cast<const float4*>(f + (size_t)i * 8);
    float4 a = p[0], b = p[1];
    bf16x8 v = {(__bf16)a.x, (__bf16)a.y, (__bf16)a.z, (__bf16)a.w,
                (__bf16)b.x, (__bf16)b.y, (__bf16)b.z, (__bf16)b.w};
    reinterpret_cast<short8*>(o)[i] = __builtin_bit_cast(short8, v);
}

// ---------------- fused v3: 32 rows/block, waves split N, 32-VGPR acc ----------------
// MODE 0: rows = featb rows (node path)
// MODE 1: acc += featb[pair[2e]]@W1 + featb[pair[2e+1]]@W1   (== (src+dst)@W1)
// Block: 256 threads = 4 waves. Wave w owns cols [w*64, w*64+64) of ALL 32 rows.
// acc = 2 M-frags x 4 N-frags x f32x4 = 32 VGPRs -> 4 blocks/CU.
// GEMM2: h (32x256 bf16, swizzled) in 16 KB LDS; waves 0,1 each finish 16 rows.
template<int MODE>
__global__ __launch_bounds__(256, 4)
void fused_mlp_c(const short* __restrict__ featb,
                 const int* __restrict__ pair,
                 const short* __restrict__ W1T,   // [256][256] bf16 bits, transposed
                 const float* __restrict__ bias1, // [256]
                 const short* __restrict__ W2T,   // [16][256] bf16 bits, zero-padded cols
                 const float* __restrict__ bias2, // [ncols]
                 float* __restrict__ out,
                 int nrows, int ncols)
{
    __shared__ short hl[32 * D];   // 16 KB

    const int tid = threadIdx.x;
    const int lane = tid & 63;
    const int w = tid >> 6;        // wave id: owns col slice [w*64, w*64+64)
    const int l15 = lane & 15;
    const int g = lane >> 4;
    const int rowblk = blockIdx.x * 32;

    // gather pointers: frag f covers rows rowblk + f*16 + [0,16)
    const short* ap0[2];
    const short* ap1[2];
#pragma unroll
    for (int f = 0; f < 2; ++f) {
        int r = rowblk + f * 16 + l15;
        if (r > nrows - 1) r = nrows - 1;
        if constexpr (MODE == 0) {
            ap0[f] = featb + (size_t)r * D;
            ap1[f] = nullptr;
        } else {
            ap0[f] = featb + (size_t)pair[2 * r] * D;
            ap1[f] = featb + (size_t)pair[2 * r + 1] * D;
        }
    }

    f32x4 acc[2][4];
#pragma unroll
    for (int f = 0; f < 2; ++f)
#pragma unroll
        for (int t = 0; t < 4; ++t)
            acc[f][t] = f32x4{0.f, 0.f, 0.f, 0.f};

#pragma unroll
    for (int ks = 0; ks < 8; ++ks) {
        const int k0 = ks * 32 + g * 8;
        short8 s0 = *reinterpret_cast<const short8*>(ap0[0] + k0);
        short8 s1 = *reinterpret_cast<const short8*>(ap0[1] + k0);
        short8 d0, d1;
        if constexpr (MODE == 1) {
            d0 = *reinterpret_cast<const short8*>(ap1[0] + k0);
            d1 = *reinterpret_cast<const short8*>(ap1[1] + k0);
        }
#pragma unroll
        for (int t = 0; t < 4; ++t) {
            const int ncol = w * 4 + t;   // N-tile index 0..15
            short8 bw = *reinterpret_cast<const short8*>(W1T + ((ncol * 16 + l15) * D + k0));
            acc[0][t] = __builtin_amdgcn_mfma_f32_16x16x32_bf16(s0, bw, acc[0][t], 0, 0, 0);
            acc[1][t] = __builtin_amdgcn_mfma_f32_16x16x32_bf16(s1, bw, acc[1][t], 0, 0, 0);
            if constexpr (MODE == 1) {
                acc[0][t] = __builtin_amdgcn_mfma_f32_16x16x32_bf16(d0, bw, acc[0][t], 0, 0, 0);
                acc[1][t] = __builtin_amdgcn_mfma_f32_16x16x32_bf16(d1, bw, acc[1][t], 0, 0, 0);
            }
        }
    }

    // bias + relu -> swizzled LDS.  XOR swizzle on 16B chunks kills the 512B-row
    // stride bank conflict for the GEMM2 ds_read_b128s.
#pragma unroll
    for (int f = 0; f < 2; ++f) {
#pragma unroll
        for (int t = 0; t < 4; ++t) {
            const int col = w * 64 + t * 16 + l15;
            const float b = bias1[col];
            const int chunk = col >> 3;
#pragma unroll
            for (int r = 0; r < 4; ++r) {
                const int row = f * 16 + g * 4 + r;
                float v = fmaxf(acc[f][t][r] + b, 0.f);
                hl[row * D + (((chunk ^ (row & 7)) << 3) | (col & 7))] = f2bs(v);
            }
        }
    }

    __syncthreads();

    // GEMM2: h(32x256) @ W2(256x16-padded); wave w<2 handles M-frag w.
    if (w < 2) {
        f32x4 a2 = f32x4{0.f, 0.f, 0.f, 0.f};
        const int row = w * 16 + l15;
#pragma unroll
        for (int ks = 0; ks < 8; ++ks) {
            const int k0 = ks * 32 + g * 8;
            const int chunk = k0 >> 3;
            short8 bw = *reinterpret_cast<const short8*>(W2T + (l15 * D + k0));
            short8 ah = *reinterpret_cast<const short8*>(&hl[row * D + ((chunk ^ (row & 7)) << 3)]);
            a2 = __builtin_amdgcn_mfma_f32_16x16x32_bf16(ah, bw, a2, 0, 0, 0);
        }
        if (l15 < ncols) {
            const float b2 = bias2[l15];
#pragma unroll
            for (int r = 0; r < 4; ++r) {
                const int grow = rowblk + w * 16 + g * 4 + r;
                if (grow < nrows)
                    out[(size_t)grow * ncols + l15] = a2[r] + b2;
            }
        }
    }
}

// ---------------- fallback (fp32 gathers, proven in round 1) ----------------
template<int MODE>
__global__ __launch_bounds__(256, 2)
void fused_mlp(const float* __restrict__ feat,
               const int* __restrict__ pair,
               const short* __restrict__ W1T,
               const float* __restrict__ bias1,
               const short* __restrict__ W2T,
               const float* __restrict__ bias2,
               float* __restrict__ out,
               int nrows, int ncols)
{
    __shared__ short hl[128 * D];

    const int tid = threadIdx.x;
    const int lane = tid & 63;
    const int w = tid >> 6;
    const int l15 = lane & 15;
    const int g = lane >> 4;
    const int rowblk = blockIdx.x * 128 + w * 32;

    const float* ap0[2];
    const float* ap1[2];
#pragma unroll
    for (int f = 0; f < 2; ++f) {
        int r = rowblk + f * 16 + l15;
        if (r > nrows - 1) r = nrows - 1;
        if constexpr (MODE == 0) {
            ap0[f] = feat + (size_t)r * D;
            ap1[f] = nullptr;
        } else {
            ap0[f] = feat + (size_t)pair[2 * r] * D;
            ap1[f] = feat + (size_t)pair[2 * r + 1] * D;
        }
    }

    f32x4 acc[2][16];
#pragma unroll
    for (int f = 0; f < 2; ++f)
#pragma unroll
        for (int t = 0; t < 16; ++t)
            acc[f][t] = f32x4{0.f, 0.f, 0.f, 0.f};

#pragma unroll
    for (int ks = 0; ks < 8; ++ks) {
        const int k0 = ks * 32 + g * 8;
        short8 af[2];
#pragma unroll
        for (int f = 0; f < 2; ++f) {
            const float4* p0 = reinterpret_cast<const float4*>(ap0[f] + k0);
            float4 x0 = p0[0], x1 = p0[1];
            if constexpr (MODE == 1) {
                const float4* p1 = reinterpret_cast<const float4*>(ap1[f] + k0);
                float4 y0 = p1[0], y1 = p1[1];
                x0.x += y0.x; x0.y += y0.y; x0.z += y0.z; x0.w += y0.w;
                x1.x += y1.x; x1.y += y1.y; x1.z += y1.z; x1.w += y1.w;
            }
            bf16x8 bv = {(__bf16)x0.x, (__bf16)x0.y, (__bf16)x0.z, (__bf16)x0.w,
                         (__bf16)x1.x, (__bf16)x1.y, (__bf16)x1.z, (__bf16)x1.w};
            af[f] = __builtin_bit_cast(short8, bv);
        }
#pragma unroll
        for (int t = 0; t < 16; ++t) {
            short8 bw = *reinterpret_cast<const short8*>(W1T + ((t * 16 + l15) * D + k0));
            acc[0][t] = __builtin_amdgcn_mfma_f32_16x16x32_bf16(af[0], bw, acc[0][t], 0, 0, 0);
            acc[1][t] = __builtin_amdgcn_mfma_f32_16x16x32_bf16(af[1], bw, acc[1][t], 0, 0, 0);
        }
    }

#pragma unroll
    for (int t = 0; t < 16; ++t) {
        const int col = t * 16 + l15;
        const float b = bias1[col];
        const int chunk = col >> 3;
#pragma unroll
        for (int f = 0; f < 2; ++f) {
#pragma unroll
            for (int r = 0; r < 4; ++r) {
                const int rl = w * 32 + f * 16 + g * 4 + r;
                float v = fmaxf(acc[f][t][r] + b, 0.f);
                hl[rl * D + ((chunk ^ (rl & 7)) << 3) + (col & 7)] = f2bs(v);
            }
        }
    }

    __syncthreads();

    f32x4 acc2[2];
    acc2[0] = f32x4{0.f, 0.f, 0.f, 0.f};
    acc2[1] = f32x4{0.f, 0.f, 0.f, 0.f};
#pragma unroll
    for (int ks = 0; ks < 8; ++ks) {
        const int k0 = ks * 32 + g * 8;
        const int chunk = k0 >> 3;
        short8 bw = *reinterpret_cast<const short8*>(W2T + (l15 * D + k0));
#pragma unroll
        for (int f = 0; f < 2; ++f) {
            const int rl = w * 32 + f * 16 + l15;
            short8 ah = *reinterpret_cast<const short8*>(&hl[rl * D + ((chunk ^ (rl & 7)) << 3)]);
            acc2[f] = __builtin_amdgcn_mfma_f32_16x16x32_bf16(ah, bw, acc2[f], 0, 0, 0);
        }
    }

    if (l15 < ncols) {
        const float b2 = bias2[l15];
#pragma unroll
        for (int f = 0; f < 2; ++f) {
#pragma unroll
            for (int r = 0; r < 4; ++r) {
                const int grow = rowblk + f * 16 + g * 4 + r;
                if (grow < nrows)
                    out[(size_t)grow * ncols + l15] = acc2[f][r] + b2;
            }
        }
    }
}

// ---------------- launch ----------------

extern "C" void kernel_launch(void* const* d_in, const int* in_sizes, int n_in,
                              void* d_out, int out_size, void* d_ws, size_t ws_size,
                              hipStream_t stream)
{
    const float* node_feat = (const float*)d_in[0];
    const int*   pair_idx  = (const int*)d_in[1];
    const float* W_agg     = (const float*)d_in[2];
    const float* b_agg     = (const float*)d_in[3];
    const float* We1       = (const float*)d_in[4];
    const float* be1       = (const float*)d_in[5];
    const float* We2       = (const float*)d_in[6];
    const float* be2       = (const float*)d_in[7];
    const float* Wn1       = (const float*)d_in[8];
    const float* bn1       = (const float*)d_in[9];
    const float* Wn2       = (const float*)d_in[10];
    const float* bn2       = (const float*)d_in[11];

    const int N = in_sizes[0] / D;   // 100000
    const int E = in_sizes[1] / 2;   // 262144

    float* out = (float*)d_out;
    char*  ws  = (char*)d_ws;

    short* WcT  = (short*)(ws + 0);        // 128 KB
    short* Wn1T = (short*)(ws + 131072);   // 128 KB
    short* We2T = (short*)(ws + 262144);   // 8 KB
    short* Wn2T = (short*)(ws + 270336);   // 8 KB
    float* bc   = (float*)(ws + 278528);   // 1 KB
    const size_t FEATB_OFF = 524288;
    short* featb = (short*)(ws + FEATB_OFF);  // N*D*2 = 51.2 MB
    const size_t need = FEATB_OFF + (size_t)N * D * 2;

    pre_bc<<<1, 256, 0, stream>>>(b_agg, We1, be1, bc);
    pre_wct<<<D, 256, 0, stream>>>(W_agg, We1, WcT);
    pre_wn1t<<<D, 256, 0, stream>>>(Wn1, Wn1T);
    pre_w2t<<<1, 256, 0, stream>>>(We2, Wn2, We2T, Wn2T);

    if (ws_size >= need) {
        const int n8 = N * D / 8;
        pre_featb<<<(n8 + 255) / 256, 256, 0, stream>>>(node_feat, featb, n8);

        fused_mlp_c<0><<<(N + 31) / 32, 256, 0, stream>>>(
            featb, nullptr, Wn1T, bn1, Wn2T, bn2, out, N, 2);

        fused_mlp_c<1><<<(E + 31) / 32, 256, 0, stream>>>(
            featb, pair_idx, WcT, bc, We2T, be2, out + (size_t)2 * N, E, 5);
    } else {
        fused_mlp<0><<<(N + 127) / 128, 256, 0, stream>>>(
            node_feat, nullptr, Wn1T, bn1, Wn2T, bn2, out, N, 2);

        fused_mlp<1><<<E / 128, 256, 0, stream>>>(
            node_feat, pair_idx, WcT, bc, We2T, be2, out + (size_t)2 * N, E, 5);
    }
}

// Round 4
// 211.200 us; speedup vs baseline: 1.7961x; 1.7961x over previous
//
#include <hip/hip_runtime.h>

#define D 256

typedef float f32x4 __attribute__((ext_vector_type(4)));
typedef short short8 __attribute__((ext_vector_type(8)));
typedef __bf16 bf16x8 __attribute__((ext_vector_type(8)));

static __device__ __forceinline__ short f2bs(float f) {
    __bf16 b = (__bf16)f;
    return __builtin_bit_cast(short, b);
}
static __device__ __forceinline__ float bs2f(short s) {
    unsigned u = ((unsigned)(unsigned short)s) << 16;
    return __builtin_bit_cast(float, u);
}

// ---------------- precompute kernels (run every call; deterministic) ----------------

__global__ void pre_bc(const float* __restrict__ b_agg, const float* __restrict__ We1,
                       const float* __restrict__ be1, float* __restrict__ bc)
{
    int j = threadIdx.x;
    float acc = be1[j];
    for (int k = 0; k < D; ++k)
        acc += 2.f * b_agg[k] * We1[k * D + j];
    bc[j] = acc;
}

// Ws[i][k] = W_agg[i*D+k] + W_agg[(i+D)*D+k]; Wc[i][j] = sum_k Ws[i][k]*We1[k][j]
// stored transposed: WcT[j*D+i]
__global__ void pre_wct(const float* __restrict__ W_agg, const float* __restrict__ We1,
                        short* __restrict__ WcT)
{
    __shared__ float wsrow[D];
    int i = blockIdx.x, j = threadIdx.x;
    wsrow[j] = W_agg[i * D + j] + W_agg[(i + D) * D + j];
    __syncthreads();
    float acc = 0.f;
    for (int k = 0; k < D; ++k)
        acc += wsrow[k] * We1[k * D + j];
    WcT[j * D + i] = f2bs(acc);
}

__global__ void pre_wn1t(const float* __restrict__ Wn1, short* __restrict__ Wn1T)
{
    int i = blockIdx.x, j = threadIdx.x;
    Wn1T[j * D + i] = f2bs(Wn1[i * D + j]);
}

__global__ void pre_w2t(const float* __restrict__ We2, const float* __restrict__ Wn2,
                        short* __restrict__ We2T, short* __restrict__ Wn2T)
{
    int k = threadIdx.x;
    for (int c = 0; c < 16; ++c) {
        float ve = (c < 5) ? We2[k * 5 + c] : 0.f;
        float vn = (c < 2) ? Wn2[k * 2 + c] : 0.f;
        We2T[c * D + k] = f2bs(ve);
        Wn2T[c * D + k] = f2bs(vn);
    }
}

// node_feat (fp32) -> bf16 cache in ws
__global__ void pre_featb(const float* __restrict__ f, short* __restrict__ o, int n8)
{
    int i = blockIdx.x * blockDim.x + threadIdx.x;
    if (i >= n8) return;
    const float4* p = reinterpret_cast<const float4*>(f + (size_t)i * 8);
    float4 a = p[0], b = p[1];
    bf16x8 v = {(__bf16)a.x, (__bf16)a.y, (__bf16)a.z, (__bf16)a.w,
                (__bf16)b.x, (__bf16)b.y, (__bf16)b.z, (__bf16)b.w};
    reinterpret_cast<short8*>(o)[i] = __builtin_bit_cast(short8, v);
}

// ---------------- fused v4: async-staged gathers -> LDS, dense LDS GEMM ----------------
// TILE = 64 rows/block, 4 waves.
// Stage: wave w gathers rows [w*16, w*16+16): issue ALL 16B-chunk loads up front
//   (src+dst for MODE 1), sum to one bf16 row, write chunk-XOR-swizzled LDS.
// GEMM1: col-split; wave w owns cols [w*64,w*64+64): 4 M-frags x 4 N-tiles (acc=64 VGPR).
//   Per k-step: 4 ds_read_b128 + 4 L2-hot weight loads -> 16 MFMAs.
// sA buffer is reused for h (extra barrier); GEMM2 row-split: wave w rows [w*16,+16).
template<int MODE>
__global__ __launch_bounds__(256, 3)
void fused_mlp_d(const short* __restrict__ featb,
                 const int* __restrict__ pair,
                 const short* __restrict__ W1T,   // [256][256] bf16 bits, transposed
                 const float* __restrict__ bias1, // [256]
                 const short* __restrict__ W2T,   // [16][256] bf16 bits, zero-padded cols
                 const float* __restrict__ bias2, // [ncols]
                 float* __restrict__ out,
                 int nrows, int ncols)
{
    __shared__ __align__(16) short sbuf[64 * D];   // 32 KB: staged rows, then h

    const int tid = threadIdx.x;
    const int lane = tid & 63;
    const int w = tid >> 6;
    const int l15 = lane & 15;
    const int g = lane >> 4;
    const int rowblk = blockIdx.x * 64;

    // ---- stage 16 (summed) rows per wave into sbuf, chunk-swizzled ----
    {
        const int c = lane & 31;        // logical 16B chunk within row, 0..31
        const int rsub = lane >> 5;     // 0/1: which of the 2 rows this lane serves
        int pv = 0;
        if constexpr (MODE == 1) {
            if (lane < 32) pv = pair[2 * (rowblk + w * 16) + lane];  // 16 edges x {src,dst}
        }
        short8 sv[8], dv[8];
#pragma unroll
        for (int j = 0; j < 8; ++j) {
            const int rl = 2 * j + rsub;          // row within wave, 0..15
            size_t src;
            if constexpr (MODE == 1) {
                src = (size_t)(unsigned)__shfl(pv, 2 * rl);
            } else {
                int r = rowblk + w * 16 + rl;
                if (r > nrows - 1) r = nrows - 1;
                src = (size_t)r;
            }
            sv[j] = *reinterpret_cast<const short8*>(featb + src * D + c * 8);
            if constexpr (MODE == 1) {
                size_t dst = (size_t)(unsigned)__shfl(pv, 2 * rl + 1);
                dv[j] = *reinterpret_cast<const short8*>(featb + dst * D + c * 8);
            }
        }
#pragma unroll
        for (int j = 0; j < 8; ++j) {
            const int rl = 2 * j + rsub;
            const int row = w * 16 + rl;
            short8 v;
            if constexpr (MODE == 1) {
#pragma unroll
                for (int i = 0; i < 8; ++i)
                    v[i] = f2bs(bs2f(sv[j][i]) + bs2f(dv[j][i]));
            } else {
                v = sv[j];
            }
            *reinterpret_cast<short8*>(&sbuf[row * D + ((c ^ (row & 7)) * 8)]) = v;
        }
    }
    __syncthreads();

    // ---- GEMM1: 64 rows x 256 cols, wave w does cols [w*64, w*64+64) ----
    f32x4 acc[4][4];
#pragma unroll
    for (int f = 0; f < 4; ++f)
#pragma unroll
        for (int t = 0; t < 4; ++t)
            acc[f][t] = f32x4{0.f, 0.f, 0.f, 0.f};

#pragma unroll
    for (int ks = 0; ks < 8; ++ks) {
        const int k0 = ks * 32 + g * 8;
        const int c = ks * 4 + g;
        short8 a[4];
#pragma unroll
        for (int f = 0; f < 4; ++f) {
            const int row = f * 16 + l15;
            a[f] = *reinterpret_cast<const short8*>(&sbuf[row * D + ((c ^ (row & 7)) * 8)]);
        }
#pragma unroll
        for (int t = 0; t < 4; ++t) {
            short8 bw = *reinterpret_cast<const short8*>(W1T + ((w * 4 + t) * 16 + l15) * D + k0);
#pragma unroll
            for (int f = 0; f < 4; ++f)
                acc[f][t] = __builtin_amdgcn_mfma_f32_16x16x32_bf16(a[f], bw, acc[f][t], 0, 0, 0);
        }
    }

    __syncthreads();   // all GEMM1 reads of sbuf done before h overwrites it

    // ---- bias + relu -> h into sbuf (chunk-swizzled) ----
#pragma unroll
    for (int t = 0; t < 4; ++t) {
        const int col = w * 64 + t * 16 + l15;
        const float b = bias1[col];
        const int chunk = col >> 3;
#pragma unroll
        for (int f = 0; f < 4; ++f) {
#pragma unroll
            for (int r = 0; r < 4; ++r) {
                const int row = f * 16 + g * 4 + r;
                float v = fmaxf(acc[f][t][r] + b, 0.f);
                sbuf[row * D + (((chunk ^ (row & 7)) << 3) | (col & 7))] = f2bs(v);
            }
        }
    }

    __syncthreads();

    // ---- GEMM2: h(64x256) @ W2(256x16-padded); wave w does rows [w*16, w*16+16) ----
    f32x4 a2 = f32x4{0.f, 0.f, 0.f, 0.f};
    const int row = w * 16 + l15;
#pragma unroll
    for (int ks = 0; ks < 8; ++ks) {
        const int k0 = ks * 32 + g * 8;
        const int c = ks * 4 + g;
        short8 bw = *reinterpret_cast<const short8*>(W2T + l15 * D + k0);
        short8 ah = *reinterpret_cast<const short8*>(&sbuf[row * D + ((c ^ (row & 7)) * 8)]);
        a2 = __builtin_amdgcn_mfma_f32_16x16x32_bf16(ah, bw, a2, 0, 0, 0);
    }

    if (l15 < ncols) {
        const float b2 = bias2[l15];
#pragma unroll
        for (int r = 0; r < 4; ++r) {
            const int grow = rowblk + w * 16 + g * 4 + r;
            if (grow < nrows)
                out[(size_t)grow * ncols + l15] = a2[r] + b2;
        }
    }
}

// ---------------- fallback (fp32 gathers, proven in round 1) ----------------
template<int MODE>
__global__ __launch_bounds__(256, 2)
void fused_mlp(const float* __restrict__ feat,
               const int* __restrict__ pair,
               const short* __restrict__ W1T,
               const float* __restrict__ bias1,
               const short* __restrict__ W2T,
               const float* __restrict__ bias2,
               float* __restrict__ out,
               int nrows, int ncols)
{
    __shared__ short hl[128 * D];

    const int tid = threadIdx.x;
    const int lane = tid & 63;
    const int w = tid >> 6;
    const int l15 = lane & 15;
    const int g = lane >> 4;
    const int rowblk = blockIdx.x * 128 + w * 32;

    const float* ap0[2];
    const float* ap1[2];
#pragma unroll
    for (int f = 0; f < 2; ++f) {
        int r = rowblk + f * 16 + l15;
        if (r > nrows - 1) r = nrows - 1;
        if constexpr (MODE == 0) {
            ap0[f] = feat + (size_t)r * D;
            ap1[f] = nullptr;
        } else {
            ap0[f] = feat + (size_t)pair[2 * r] * D;
            ap1[f] = feat + (size_t)pair[2 * r + 1] * D;
        }
    }

    f32x4 acc[2][16];
#pragma unroll
    for (int f = 0; f < 2; ++f)
#pragma unroll
        for (int t = 0; t < 16; ++t)
            acc[f][t] = f32x4{0.f, 0.f, 0.f, 0.f};

#pragma unroll
    for (int ks = 0; ks < 8; ++ks) {
        const int k0 = ks * 32 + g * 8;
        short8 af[2];
#pragma unroll
        for (int f = 0; f < 2; ++f) {
            const float4* p0 = reinterpret_cast<const float4*>(ap0[f] + k0);
            float4 x0 = p0[0], x1 = p0[1];
            if constexpr (MODE == 1) {
                const float4* p1 = reinterpret_cast<const float4*>(ap1[f] + k0);
                float4 y0 = p1[0], y1 = p1[1];
                x0.x += y0.x; x0.y += y0.y; x0.z += y0.z; x0.w += y0.w;
                x1.x += y1.x; x1.y += y1.y; x1.z += y1.z; x1.w += y1.w;
            }
            bf16x8 bv = {(__bf16)x0.x, (__bf16)x0.y, (__bf16)x0.z, (__bf16)x0.w,
                         (__bf16)x1.x, (__bf16)x1.y, (__bf16)x1.z, (__bf16)x1.w};
            af[f] = __builtin_bit_cast(short8, bv);
        }
#pragma unroll
        for (int t = 0; t < 16; ++t) {
            short8 bw = *reinterpret_cast<const short8*>(W1T + ((t * 16 + l15) * D + k0));
            acc[0][t] = __builtin_amdgcn_mfma_f32_16x16x32_bf16(af[0], bw, acc[0][t], 0, 0, 0);
            acc[1][t] = __builtin_amdgcn_mfma_f32_16x16x32_bf16(af[1], bw, acc[1][t], 0, 0, 0);
        }
    }

#pragma unroll
    for (int t = 0; t < 16; ++t) {
        const int col = t * 16 + l15;
        const float b = bias1[col];
        const int chunk = col >> 3;
#pragma unroll
        for (int f = 0; f < 2; ++f) {
#pragma unroll
            for (int r = 0; r < 4; ++r) {
                const int rl = w * 32 + f * 16 + g * 4 + r;
                float v = fmaxf(acc[f][t][r] + b, 0.f);
                hl[rl * D + ((chunk ^ (rl & 7)) << 3) + (col & 7)] = f2bs(v);
            }
        }
    }

    __syncthreads();

    f32x4 acc2[2];
    acc2[0] = f32x4{0.f, 0.f, 0.f, 0.f};
    acc2[1] = f32x4{0.f, 0.f, 0.f, 0.f};
#pragma unroll
    for (int ks = 0; ks < 8; ++ks) {
        const int k0 = ks * 32 + g * 8;
        const int chunk = k0 >> 3;
        short8 bw = *reinterpret_cast<const short8*>(W2T + (l15 * D + k0));
#pragma unroll
        for (int f = 0; f < 2; ++f) {
            const int rl = w * 32 + f * 16 + l15;
            short8 ah = *reinterpret_cast<const short8*>(&hl[rl * D + ((chunk ^ (rl & 7)) << 3)]);
            acc2[f] = __builtin_amdgcn_mfma_f32_16x16x32_bf16(ah, bw, acc2[f], 0, 0, 0);
        }
    }

    if (l15 < ncols) {
        const float b2 = bias2[l15];
#pragma unroll
        for (int f = 0; f < 2; ++f) {
#pragma unroll
            for (int r = 0; r < 4; ++r) {
                const int grow = rowblk + f * 16 + g * 4 + r;
                if (grow < nrows)
                    out[(size_t)grow * ncols + l15] = acc2[f][r] + b2;
            }
        }
    }
}

// ---------------- launch ----------------

extern "C" void kernel_launch(void* const* d_in, const int* in_sizes, int n_in,
                              void* d_out, int out_size, void* d_ws, size_t ws_size,
                              hipStream_t stream)
{
    const float* node_feat = (const float*)d_in[0];
    const int*   pair_idx  = (const int*)d_in[1];
    const float* W_agg     = (const float*)d_in[2];
    const float* b_agg     = (const float*)d_in[3];
    const float* We1       = (const float*)d_in[4];
    const float* be1       = (const float*)d_in[5];
    const float* We2       = (const float*)d_in[6];
    const float* be2       = (const float*)d_in[7];
    const float* Wn1       = (const float*)d_in[8];
    const float* bn1       = (const float*)d_in[9];
    const float* Wn2       = (const float*)d_in[10];
    const float* bn2       = (const float*)d_in[11];

    const int N = in_sizes[0] / D;   // 100000
    const int E = in_sizes[1] / 2;   // 262144

    float* out = (float*)d_out;
    char*  ws  = (char*)d_ws;

    short* WcT  = (short*)(ws + 0);        // 128 KB
    short* Wn1T = (short*)(ws + 131072);   // 128 KB
    short* We2T = (short*)(ws + 262144);   // 8 KB
    short* Wn2T = (short*)(ws + 270336);   // 8 KB
    float* bc   = (float*)(ws + 278528);   // 1 KB
    const size_t FEATB_OFF = 524288;
    short* featb = (short*)(ws + FEATB_OFF);  // N*D*2 = 51.2 MB
    const size_t need = FEATB_OFF + (size_t)N * D * 2;

    pre_bc<<<1, 256, 0, stream>>>(b_agg, We1, be1, bc);
    pre_wct<<<D, 256, 0, stream>>>(W_agg, We1, WcT);
    pre_wn1t<<<D, 256, 0, stream>>>(Wn1, Wn1T);
    pre_w2t<<<1, 256, 0, stream>>>(We2, Wn2, We2T, Wn2T);

    if (ws_size >= need) {
        const int n8 = N * D / 8;
        pre_featb<<<(n8 + 255) / 256, 256, 0, stream>>>(node_feat, featb, n8);

        fused_mlp_d<0><<<(N + 63) / 64, 256, 0, stream>>>(
            featb, nullptr, Wn1T, bn1, Wn2T, bn2, out, N, 2);

        fused_mlp_d<1><<<(E + 63) / 64, 256, 0, stream>>>(
            featb, pair_idx, WcT, bc, We2T, be2, out + (size_t)2 * N, E, 5);
    } else {
        fused_mlp<0><<<(N + 127) / 128, 256, 0, stream>>>(
            node_feat, nullptr, Wn1T, bn1, Wn2T, bn2, out, N, 2);

        fused_mlp<1><<<E / 128, 256, 0, stream>>>(
            node_feat, pair_idx, WcT, bc, We2T, be2, out + (size_t)2 * N, E, 5);
    }
}